// Round 6
// baseline (235.022 us; speedup 1.0000x reference)
//
#include <hip/hip_runtime.h>

// Problem constants (fixed by the reference): n=8, c=16, H=W=512.
#define NIMG 8
#define NCLS 16
#define HW   262144            // 512*512 = 2^18 pixels per image
#define NBLK 2048              // 256 threads x 4 px = 1024 px/block; 256 blocks/image

// ---------------------------------------------------------------------------
// Main pass — full-occupancy register streaming, no LDS staging.
// __launch_bounds__(256, 8): VGPR<=64 -> 8 blocks/CU = 32 waves/CU (copy-like
// occupancy; read concurrency from TLP, not per-wave queue depth).
// Each thread owns 4 consecutive pixels; 16 channels processed as two
// half-passes of 8 float4 loads (8 KB/wave burst), exact max within a half,
// online logsumexp merge across halves.
// ---------------------------------------------------------------------------
__global__ __launch_bounds__(256, 8) void dwce_main(const float* __restrict__ pred,
                                                    const int* __restrict__ tgt,
                                                    float* __restrict__ partials) {
    __shared__ float s_bin[32];   // [0..15] sum(lp_t) per class, [16..31] count
    const int tid = threadIdx.x;
    if (tid < 32) s_bin[tid] = 0.0f;
    __syncthreads();

    const int gid = blockIdx.x * 256 + tid;
    const long long p0 = (long long)gid * 4;       // 4 consecutive pixels, one image
    const int n_img = (int)(p0 >> 18);
    const int hw    = (int)(p0 & (HW - 1));
    const float* base = pred + (size_t)n_img * NCLS * HW + hw;

    const int4 t4 = *(const int4*)(tgt + p0);

    float4 m1, s1, m2, s2;
    float4 xt = make_float4(0.f, 0.f, 0.f, 0.f);

    // ---- half 1: channels 0..7 ----
    {
        float4 v[8];
#pragma unroll
        for (int j = 0; j < 8; ++j)
            v[j] = *(const float4*)(base + (size_t)j * HW);
        m1 = v[0];
#pragma unroll
        for (int j = 1; j < 8; ++j) {
            m1.x = fmaxf(m1.x, v[j].x);
            m1.y = fmaxf(m1.y, v[j].y);
            m1.z = fmaxf(m1.z, v[j].z);
            m1.w = fmaxf(m1.w, v[j].w);
        }
        s1 = make_float4(0.f, 0.f, 0.f, 0.f);
#pragma unroll
        for (int j = 0; j < 8; ++j) {
            s1.x += __expf(v[j].x - m1.x);
            s1.y += __expf(v[j].y - m1.y);
            s1.z += __expf(v[j].z - m1.z);
            s1.w += __expf(v[j].w - m1.w);
            if (t4.x == j) xt.x = v[j].x;   // -> v_cndmask, no divergence
            if (t4.y == j) xt.y = v[j].y;
            if (t4.z == j) xt.z = v[j].z;
            if (t4.w == j) xt.w = v[j].w;
        }
    }
    // ---- half 2: channels 8..15 ----
    {
        float4 v[8];
#pragma unroll
        for (int j = 0; j < 8; ++j)
            v[j] = *(const float4*)(base + (size_t)(8 + j) * HW);
        m2 = v[0];
#pragma unroll
        for (int j = 1; j < 8; ++j) {
            m2.x = fmaxf(m2.x, v[j].x);
            m2.y = fmaxf(m2.y, v[j].y);
            m2.z = fmaxf(m2.z, v[j].z);
            m2.w = fmaxf(m2.w, v[j].w);
        }
        s2 = make_float4(0.f, 0.f, 0.f, 0.f);
#pragma unroll
        for (int j = 0; j < 8; ++j) {
            s2.x += __expf(v[j].x - m2.x);
            s2.y += __expf(v[j].y - m2.y);
            s2.z += __expf(v[j].z - m2.z);
            s2.w += __expf(v[j].w - m2.w);
            if (t4.x == 8 + j) xt.x = v[j].x;
            if (t4.y == 8 + j) xt.y = v[j].y;
            if (t4.z == 8 + j) xt.z = v[j].z;
            if (t4.w == 8 + j) xt.w = v[j].w;
        }
    }

    // merge the two halves: m = max(m1,m2); s = s1*e^(m1-m) + s2*e^(m2-m)
    float4 m;
    m.x = fmaxf(m1.x, m2.x);
    m.y = fmaxf(m1.y, m2.y);
    m.z = fmaxf(m1.z, m2.z);
    m.w = fmaxf(m1.w, m2.w);
    float4 s;
    s.x = s1.x * __expf(m1.x - m.x) + s2.x * __expf(m2.x - m.x);
    s.y = s1.y * __expf(m1.y - m.y) + s2.y * __expf(m2.y - m.y);
    s.z = s1.z * __expf(m1.z - m.z) + s2.z * __expf(m2.z - m.z);
    s.w = s1.w * __expf(m1.w - m.w) + s2.w * __expf(m2.w - m.w);

    const float lp0 = xt.x - (m.x + __logf(s.x));
    const float lp1 = xt.y - (m.y + __logf(s.y));
    const float lp2 = xt.z - (m.z + __logf(s.z));
    const float lp3 = xt.w - (m.w + __logf(s.w));

    atomicAdd(&s_bin[t4.x], lp0);
    atomicAdd(&s_bin[t4.y], lp1);
    atomicAdd(&s_bin[t4.z], lp2);
    atomicAdd(&s_bin[t4.w], lp3);
    atomicAdd(&s_bin[16 + t4.x], 1.0f);
    atomicAdd(&s_bin[16 + t4.y], 1.0f);
    atomicAdd(&s_bin[16 + t4.z], 1.0f);
    atomicAdd(&s_bin[16 + t4.w], 1.0f);

    __syncthreads();
    if (tid < 32)   // non-atomic per-block partials, c-major: partials[c][block]
        partials[(size_t)tid * NBLK + blockIdx.x] = s_bin[tid];
}

// ---------------------------------------------------------------------------
// Finalize: reduce 2048 block-partials per bin, build w_class from global
// counts, compute -mean_n(num/den). Single block, 256 threads.
// Image n owns blocks [n*256, (n+1)*256) -> contiguous 256 floats per (c,n).
// ---------------------------------------------------------------------------
__global__ __launch_bounds__(256) void dwce_final(const float* __restrict__ ws,
                                                  float* __restrict__ out) {
    __shared__ float tot[32][NIMG];   // [c(0..31)][n]
    __shared__ float wcl[NCLS];
    __shared__ float ratio[NIMG];
    const int tid = threadIdx.x;
    const int c = tid >> 3;           // 0..31
    const int n = tid & 7;            // 0..7

    const float4* p = (const float4*)(ws + (size_t)c * NBLK + n * 256);
    float4 a = make_float4(0.f, 0.f, 0.f, 0.f);
#pragma unroll 8
    for (int k = 0; k < 64; ++k) {
        float4 q = p[k];
        a.x += q.x; a.y += q.y; a.z += q.z; a.w += q.w;
    }
    tot[c][n] = (a.x + a.y) + (a.z + a.w);
    __syncthreads();

    if (tid < NCLS) {
        float g = 0.f;
#pragma unroll
        for (int i = 0; i < NIMG; ++i) g += tot[NCLS + tid][i];   // global count
        wcl[tid] = (g > 0.f) ? 1.0f / (g * (float)NCLS) : 0.0f;
    }
    __syncthreads();
    if (tid < NIMG) {
        float num = 0.f, den = 0.f;
#pragma unroll
        for (int c2 = 0; c2 < NCLS; ++c2) {
            num += tot[c2][tid] * wcl[c2];
            den += tot[NCLS + c2][tid] * wcl[c2];
        }
        ratio[tid] = num / den;
    }
    __syncthreads();
    if (tid == 0) {
        float r = 0.f;
#pragma unroll
        for (int i = 0; i < NIMG; ++i) r += ratio[i];
        out[0] = -r * (1.0f / (float)NIMG);
    }
}

extern "C" void kernel_launch(void* const* d_in, const int* in_sizes, int n_in,
                              void* d_out, int out_size, void* d_ws, size_t ws_size,
                              hipStream_t stream) {
    const float* pred = (const float*)d_in[0];
    const int*   tgt  = (const int*)d_in[1];
    // d_in[2] (weights) is ignored by the reference.
    float* out = (float*)d_out;
    float* ws  = (float*)d_ws;   // 32*NBLK floats = 256 KB, fully overwritten

    dwce_main<<<NBLK, 256, 0, stream>>>(pred, tgt, ws);
    dwce_final<<<1, 256, 0, stream>>>(ws, out);
}

// Round 7
// 211.730 us; speedup vs baseline: 1.1100x; 1.1100x over previous
//
#include <hip/hip_runtime.h>

// Problem constants (fixed by the reference): n=8, c=16, H=W=512.
#define NIMG 8
#define NCLS 16
#define HW   262144            // 512*512 = 2^18 pixels per image
#define NBLK 2048              // 256 thr x 4 px = 1024 px/block; 256 blocks/image

// ---------------------------------------------------------------------------
// Main pass — channel-major register streaming at full occupancy.
// __launch_bounds__(256, 8): 8 blocks/CU = 32 waves/CU. Only 3 float4 load
// buffers live (2-deep channel prefetch, register rotation) -> ~40 VGPRs,
// no arrays, no spills. Online logsumexp per pixel in registers. No barrier
// inside the loop: every wave keeps ~2 independent 1-KB loads in flight
// continuously (copy-kernel-like issue pattern).
// ---------------------------------------------------------------------------
__global__ __launch_bounds__(256, 8) void dwce_main(const float* __restrict__ pred,
                                                    const int* __restrict__ tgt,
                                                    float* __restrict__ partials) {
    __shared__ float s_bin[32];   // [0..15] sum(lp_t) per class, [16..31] count
    const int tid = threadIdx.x;
    if (tid < 32) s_bin[tid] = 0.0f;
    __syncthreads();              // before any loads are issued (nothing to drain)

    const int gid = blockIdx.x * 256 + tid;
    const long long p0 = (long long)gid * 4;       // 4 consecutive pixels, one image
    const int n_img = (int)(p0 >> 18);
    const int hw    = (int)(p0 & (HW - 1));
    const float* base = pred + (size_t)n_img * NCLS * HW + hw;

    const int4 t4 = *(const int4*)(tgt + p0);

    // 2-deep channel prefetch pipeline: v0 = ch c, v1 = ch c+1, vn = ch c+2.
    float4 v0 = *(const float4*)(base);
    float4 v1 = *(const float4*)(base + HW);

    float4 m  = make_float4(-3.0e38f, -3.0e38f, -3.0e38f, -3.0e38f);
    float4 s  = make_float4(0.f, 0.f, 0.f, 0.f);
    float4 xt = make_float4(0.f, 0.f, 0.f, 0.f);

#pragma unroll
    for (int c = 0; c < NCLS; ++c) {
        float4 vn = make_float4(0.f, 0.f, 0.f, 0.f);
        if (c + 2 < NCLS)
            vn = *(const float4*)(base + (size_t)(c + 2) * HW);

        // online logsumexp update with v0 (channel c)
        float4 mn;
        mn.x = fmaxf(m.x, v0.x);
        mn.y = fmaxf(m.y, v0.y);
        mn.z = fmaxf(m.z, v0.z);
        mn.w = fmaxf(m.w, v0.w);
        s.x = s.x * __expf(m.x - mn.x) + __expf(v0.x - mn.x);
        s.y = s.y * __expf(m.y - mn.y) + __expf(v0.y - mn.y);
        s.z = s.z * __expf(m.z - mn.z) + __expf(v0.z - mn.z);
        s.w = s.w * __expf(m.w - mn.w) + __expf(v0.w - mn.w);
        m = mn;
        // gather logit at target class (v_cndmask, no divergence)
        if (t4.x == c) xt.x = v0.x;
        if (t4.y == c) xt.y = v0.y;
        if (t4.z == c) xt.z = v0.z;
        if (t4.w == c) xt.w = v0.w;

        v0 = v1;
        v1 = vn;
    }

    const float lp0 = xt.x - (m.x + __logf(s.x));
    const float lp1 = xt.y - (m.y + __logf(s.y));
    const float lp2 = xt.z - (m.z + __logf(s.z));
    const float lp3 = xt.w - (m.w + __logf(s.w));

    atomicAdd(&s_bin[t4.x], lp0);
    atomicAdd(&s_bin[t4.y], lp1);
    atomicAdd(&s_bin[t4.z], lp2);
    atomicAdd(&s_bin[t4.w], lp3);
    atomicAdd(&s_bin[16 + t4.x], 1.0f);
    atomicAdd(&s_bin[16 + t4.y], 1.0f);
    atomicAdd(&s_bin[16 + t4.z], 1.0f);
    atomicAdd(&s_bin[16 + t4.w], 1.0f);

    __syncthreads();
    if (tid < 32)   // non-atomic per-block partials, c-major: partials[c][block]
        partials[(size_t)tid * NBLK + blockIdx.x] = s_bin[tid];
}

// ---------------------------------------------------------------------------
// Finalize: reduce 2048 block-partials per bin, build w_class from global
// counts, compute -mean_n(num/den). Single block, 256 threads.
// Image n owns blocks [n*256, (n+1)*256) -> contiguous 256 floats per (c,n).
// ---------------------------------------------------------------------------
__global__ __launch_bounds__(256) void dwce_final(const float* __restrict__ ws,
                                                  float* __restrict__ out) {
    __shared__ float tot[32][NIMG];   // [c(0..31)][n]
    __shared__ float wcl[NCLS];
    __shared__ float ratio[NIMG];
    const int tid = threadIdx.x;
    const int c = tid >> 3;           // 0..31
    const int n = tid & 7;            // 0..7

    const float4* p = (const float4*)(ws + (size_t)c * NBLK + n * 256);
    float4 a = make_float4(0.f, 0.f, 0.f, 0.f);
#pragma unroll 8
    for (int k = 0; k < 64; ++k) {
        float4 q = p[k];
        a.x += q.x; a.y += q.y; a.z += q.z; a.w += q.w;
    }
    tot[c][n] = (a.x + a.y) + (a.z + a.w);
    __syncthreads();

    if (tid < NCLS) {
        float g = 0.f;
#pragma unroll
        for (int i = 0; i < NIMG; ++i) g += tot[NCLS + tid][i];   // global count
        wcl[tid] = (g > 0.f) ? 1.0f / (g * (float)NCLS) : 0.0f;
    }
    __syncthreads();
    if (tid < NIMG) {
        float num = 0.f, den = 0.f;
#pragma unroll
        for (int c2 = 0; c2 < NCLS; ++c2) {
            num += tot[c2][tid] * wcl[c2];
            den += tot[NCLS + c2][tid] * wcl[c2];
        }
        ratio[tid] = num / den;
    }
    __syncthreads();
    if (tid == 0) {
        float r = 0.f;
#pragma unroll
        for (int i = 0; i < NIMG; ++i) r += ratio[i];
        out[0] = -r * (1.0f / (float)NIMG);
    }
}

extern "C" void kernel_launch(void* const* d_in, const int* in_sizes, int n_in,
                              void* d_out, int out_size, void* d_ws, size_t ws_size,
                              hipStream_t stream) {
    const float* pred = (const float*)d_in[0];
    const int*   tgt  = (const int*)d_in[1];
    // d_in[2] (weights) is ignored by the reference.
    float* out = (float*)d_out;
    float* ws  = (float*)d_ws;   // 32*NBLK floats = 256 KB, fully overwritten

    dwce_main<<<NBLK, 256, 0, stream>>>(pred, tgt, ws);
    dwce_final<<<1, 256, 0, stream>>>(ws, out);
}